// Round 6
// baseline (1558.238 us; speedup 1.0000x reference)
//
#include <hip/hip_runtime.h>
#include <hip/hip_fp16.h>

#define N_NODES 10000
#define N_EDGES 60000
#define EPAD    60032   // multiple of 128
#define CSPLIT  2
#define CT_PER  32      // 64 / CSPLIT

typedef _Float16 f16;
typedef f16 f16x8 __attribute__((ext_vector_type(8)));
typedef float f32x4 __attribute__((ext_vector_type(4)));

__device__ __forceinline__ void gload16(const void* g, void* l) {
    __builtin_amdgcn_global_load_lds((const __attribute__((address_space(1))) unsigned int*)g,
                                     (__attribute__((address_space(3))) unsigned int*)l, 16, 0, 0);
}

// combine a,b over xor-mask m: lanes with (lane&m)==0 end with a-pair-sum, else b-pair-sum
__device__ __forceinline__ float foldp(float a, float b, int m, int lane) {
    float x = (lane & m) ? b : a;
    float y = (lane & m) ? a : b;
    return x + __shfl_xor(y, m);
}

// ---------------- node encoder: h = relu(x@nW1+nb1)@nW2+nb2 ----------------
__global__ void k_node_enc(const float* __restrict__ x, const float* __restrict__ W1,
                           const float* __restrict__ b1, const float* __restrict__ W2,
                           const float* __restrict__ b2, float* __restrict__ h) {
    __shared__ float t[4][64];
    int g = threadIdx.x >> 6, j = threadIdx.x & 63;
    int node = blockIdx.x * 4 + g;
    float acc = b1[j];
#pragma unroll
    for (int i = 0; i < 6; ++i) acc += x[node * 6 + i] * W1[i * 64 + j];
    t[g][j] = fmaxf(acc, 0.f);
    __syncthreads();
    float acc2 = b2[j];
#pragma unroll
    for (int i = 0; i < 64; ++i) acc2 += t[g][i] * W2[i * 64 + j];
    h[node * 64 + j] = acc2;
}

// ---------------- condition encoder -----------------------------------------
__global__ void k_cond_enc(const float* __restrict__ cond, const float* __restrict__ scl,
                           const float* __restrict__ W1, const float* __restrict__ b1,
                           const float* __restrict__ W2, const float* __restrict__ b2,
                           float* __restrict__ u, float* __restrict__ out_u) {
    __shared__ float t[4][64];
    __shared__ float cat[4][14];
    int g = threadIdx.x >> 6, j = threadIdx.x & 63;
    if (threadIdx.x < 56) {
        int b = threadIdx.x / 14, i = threadIdx.x % 14;
        cat[b][i] = (i < 10) ? cond[b * 10 + i] : scl[b * 4 + (i - 10)];
    }
    __syncthreads();
    float acc = b1[j];
#pragma unroll
    for (int i = 0; i < 14; ++i) acc += cat[g][i] * W1[i * 64 + j];
    t[g][j] = fmaxf(acc, 0.f);
    __syncthreads();
    float acc2 = b2[j];
#pragma unroll
    for (int i = 0; i < 64; ++i) acc2 += t[g][i] * W2[i * 64 + j];
    u[g * 64 + j] = acc2;
    out_u[g * 64 + j] = acc2;
}

// ---------------- degree -----------------------------------------------------
__global__ void k_deg(const int* __restrict__ dst, float* __restrict__ deg) {
    int e = blockIdx.x * 256 + threadIdx.x;
    if (e < N_EDGES) atomicAdd(&deg[dst[e]], 1.0f);
}
__global__ void k_deg_inv(float* __restrict__ deg) {
    int n = blockIdx.x * 256 + threadIdx.x;
    if (n < N_NODES) deg[n] = 1.0f / fmaxf(deg[n], 1.0f);
}

// ------- permute kW3 into FRAGMENT-ORDERED K-HALF tiles + kb3P ---------------
// halves offset = ct*16384 + kh*8192 + ((nf*4+ks4)*64 + kg*16 + rl)*8
// element j there = kW3[k][i*64+ct] with i=nf*16+rl, k=(kh*4+ks4)*32+kg*8+j
__global__ void k_permute(const float* __restrict__ kW3, const float* __restrict__ kb3,
                          f16* __restrict__ kW3P, float* __restrict__ kb3P) {
    __shared__ float T[256][65];
    int i = blockIdx.x;                 // 0..63 (inner input index)
    int o = threadIdx.x & 63, kq = threadIdx.x >> 6;
    for (int kk = 0; kk < 64; ++kk) {
        int k = kk * 4 + kq;
        T[k][o] = kW3[(size_t)k * 4096 + i * 64 + o];
    }
    if (threadIdx.x < 64) kb3P[threadIdx.x * 64 + i] = kb3[i * 64 + threadIdx.x];
    __syncthreads();
    int ow = threadIdx.x >> 2, kc = (threadIdx.x & 3) * 64;
    int nf = i >> 4, rl = i & 15;
    for (int c = 0; c < 8; ++c) {
        int k0 = kc + c * 8;
        int ks = k0 >> 5, kh = ks >> 2, ks4 = ks & 3, kg = (k0 >> 3) & 3;
        size_t off = (size_t)ow * 16384 + kh * 8192 + ((nf * 4 + ks4) * 64 + kg * 16 + rl) * 8;
        f16x8 v;
#pragma unroll
        for (int jj = 0; jj < 8; ++jj) v[jj] = (f16)T[k0 + jj][ow];
        *(f16x8*)(kW3P + off) = v;
    }
}

// ---------------- fused edge MLP (k1 in LDS, k2 fp16 out) --------------------
__global__ __launch_bounds__(256) void k_edge12(const float* __restrict__ ea, const int* __restrict__ ei,
                                                const int* __restrict__ batch, const float* __restrict__ u,
                                                const float* __restrict__ W1, const float* __restrict__ b1,
                                                const float* __restrict__ W2, const float* __restrict__ b2,
                                                f16* __restrict__ k2) {
    __shared__ float u_s[256];
    __shared__ float ea_s[16][6];
    __shared__ int b_s[16];
    __shared__ float k1_s[16][128];
    int tid = threadIdx.x;
    int e0 = blockIdx.x * 16;
    u_s[tid] = u[tid];
    if (tid < 96) {
        int e = tid / 6, i = tid % 6;
        int eg = e0 + e;
        ea_s[e][i] = (eg < N_EDGES) ? ea[(size_t)eg * 6 + i] : 0.f;
    }
    if (tid < 16) {
        int eg = e0 + tid;
        b_s[tid] = (eg < N_EDGES) ? batch[ei[eg]] : 0;
    }
    __syncthreads();
    int j = tid & 127;
#pragma unroll 1
    for (int p = 0; p < 8; ++p) {
        int e = p * 2 + (tid >> 7);
        float acc = b1[j];
#pragma unroll
        for (int i = 0; i < 6; ++i) acc += ea_s[e][i] * W1[i * 128 + j];
        const float* ur = u_s + b_s[e] * 64;
#pragma unroll
        for (int i = 0; i < 64; ++i) acc += ur[i] * W1[(6 + i) * 128 + j];
        k1_s[e][j] = fmaxf(acc, 0.f);
    }
    __syncthreads();
    float acc2[16];
#pragma unroll
    for (int e = 0; e < 16; ++e) acc2[e] = b2[tid];
    for (int i = 0; i < 128; ++i) {
        float w = W2[(size_t)i * 256 + tid];
#pragma unroll
        for (int e = 0; e < 16; ++e) acc2[e] += k1_s[e][i] * w;
    }
#pragma unroll
    for (int e = 0; e < 16; ++e) {
        int eg = e0 + e;
        k2[(size_t)eg * 256 + tid] = (f16)((eg < N_EDGES) ? fmaxf(acc2[e], 0.f) : 0.f);
    }
}

// ---- fused GEMM + message dot + scatter-mean --------------------------------
// block = 128 edges x CT_PER col-tiles; A + h*dinv in regs; B double-buffered
// per K-HALF (16 KB) via global_load_lds; 1 barrier/half; bias from global;
// fold-reduce epilogue; 8-ct (32B-sector) deferred atomic flush.
__global__ __launch_bounds__(256, 4) void k_fused(const f16* __restrict__ A, const f16* __restrict__ Bf,
                                                  const float* __restrict__ kb3P, const float* __restrict__ h,
                                                  const int* __restrict__ ei, const float* __restrict__ dinv,
                                                  float* __restrict__ agg) {
    __shared__ __align__(16) f16 lB[2][8192];    // 2 x 16 KB
    __shared__ int src_s[128];
    __shared__ int dst_s[128];
    __shared__ float dinv_s[128];
    int tid = threadIdx.x, wave = tid >> 6, lane = tid & 63;
    int m0 = blockIdx.x * 128;
    int ct0 = blockIdx.y * CT_PER;
    if (tid < 128) {
        int eg = m0 + tid; int s = 0, d = 0; float dv = 0.f;
        if (eg < N_EDGES) { s = ei[eg]; d = ei[N_EDGES + eg]; dv = dinv[d]; }
        src_s[tid] = s; dst_s[tid] = d; dinv_s[tid] = dv;
    }
    // stage segment 0 (= ct0, k-half 0)
    {
        const f16* bp = Bf + (size_t)(ct0 * 2) * 8192;
#pragma unroll
        for (int q = 0; q < 4; ++q)
            gload16(bp + (q * 256 + tid) * 8, &lB[0][(q * 256 + wave * 64) * 8]);
    }
    __syncthreads();   // seg0 drained + src_s visible
    // A fragments: rows wave*32 + mf*16 + (lane&15), k-chunk (lane>>4)*8 + ks*32
    f16x8 a[2][8];
#pragma unroll
    for (int mf = 0; mf < 2; ++mf) {
        const f16* ap = A + (size_t)(m0 + wave * 32 + mf * 16 + (lane & 15)) * 256 + (lane >> 4) * 8;
#pragma unroll
        for (int ks = 0; ks < 8; ++ks) a[mf][ks] = *(const f16x8*)(ap + ks * 32);
    }
    // h rows (pre-scaled by dinv) in regs
    float hsr[2][4][4];
#pragma unroll
    for (int mf = 0; mf < 2; ++mf)
#pragma unroll
        for (int jj = 0; jj < 4; ++jj) {
            int el = wave * 32 + mf * 16 + (lane >> 4) * 4 + jj;
            const float* hp = h + (size_t)src_s[el] * 64 + (lane & 15);
            float dv = dinv_s[el];
#pragma unroll
            for (int nf = 0; nf < 4; ++nf) hsr[mf][jj][nf] = hp[nf * 16] * dv;
        }
    const float* bias_p = kb3P + ct0 * 64 + (lane & 15);
    int cur = 0;
#pragma unroll 1
    for (int cto = 0; cto < CT_PER; cto += 8) {
        float w8[8];
#pragma unroll
        for (int q8 = 0; q8 < 8; ++q8) {
            int ctl = cto + q8;
            // acc init = permuted bias (column-constant across rows)
            f32x4 acc[2][4];
#pragma unroll
            for (int nf = 0; nf < 4; ++nf) {
                float bv = bias_p[ctl * 64 + nf * 16];
                acc[0][nf] = {bv, bv, bv, bv};
                acc[1][nf] = {bv, bv, bv, bv};
            }
#pragma unroll
            for (int kh = 0; kh < 2; ++kh) {
                int seg = ctl * 2 + kh;
                if (seg + 1 < CT_PER * 2) {   // prefetch next k-half into alt buffer
                    const f16* bp = Bf + (size_t)(ct0 * 2 + seg + 1) * 8192;
#pragma unroll
                    for (int q = 0; q < 4; ++q)
                        gload16(bp + (q * 256 + tid) * 8, &lB[cur ^ 1][(q * 256 + wave * 64) * 8]);
                }
                const f16* lb = lB[cur];
#pragma unroll
                for (int ks4 = 0; ks4 < 4; ++ks4) {
                    f16x8 bf[4];
#pragma unroll
                    for (int nf = 0; nf < 4; ++nf)
                        bf[nf] = *(const f16x8*)(lb + (nf * 4 + ks4) * 512 + lane * 8);
#pragma unroll
                    for (int mf = 0; mf < 2; ++mf)
#pragma unroll
                        for (int nf = 0; nf < 4; ++nf)
                            acc[mf][nf] = __builtin_amdgcn_mfma_f32_16x16x32_f16(a[mf][kh * 4 + ks4], bf[nf], acc[mf][nf], 0, 0, 0);
                }
                cur ^= 1;
                __syncthreads();   // drains next-half loads; WAR on read buffer
            }
            // per-lane partials then fold-reduce (8 shfl total)
            float v[8];
#pragma unroll
            for (int mf = 0; mf < 2; ++mf)
#pragma unroll
                for (int jj = 0; jj < 4; ++jj)
                    v[mf * 4 + jj] = acc[mf][0][jj] * hsr[mf][jj][0] + acc[mf][1][jj] * hsr[mf][jj][1]
                                   + acc[mf][2][jj] * hsr[mf][jj][2] + acc[mf][3][jj] * hsr[mf][jj][3];
            float t0 = foldp(v[0], v[1], 1, lane);
            float t1 = foldp(v[2], v[3], 1, lane);
            float t2 = foldp(v[4], v[5], 1, lane);
            float t3 = foldp(v[6], v[7], 1, lane);
            float u0 = foldp(t0, t1, 2, lane);
            float u1 = foldp(t2, t3, 2, lane);
            float s0 = foldp(u0, u1, 4, lane);
            s0 += __shfl_xor(s0, 8);
            w8[q8] = s0;
        }
        // flush 8 cts = one 32B sector per edge (pad edges: dinv=0 -> adds 0.0)
        if (!(lane & 8)) {
            int mf = (lane >> 2) & 1, jj = lane & 3;
            int el = wave * 32 + mf * 16 + (lane >> 4) * 4 + jj;
            float* ap2 = agg + (size_t)dst_s[el] * 64 + ct0 + cto;
#pragma unroll
            for (int q8 = 0; q8 < 8; ++q8) atomicAdd(ap2 + q8, w8[q8]);
        }
    }
}

// ---------------- node update: h' = relu(agg + h@root + bias) ----------------
__global__ void k_update(const float* __restrict__ agg, const float* __restrict__ h,
                         const float* __restrict__ root, const float* __restrict__ bias,
                         float* __restrict__ hn) {
    __shared__ float t[4][64];
    int g = threadIdx.x >> 6, j = threadIdx.x & 63;
    int node = blockIdx.x * 4 + g;
    t[g][j] = h[node * 64 + j];
    __syncthreads();
    float acc = agg[node * 64 + j] + bias[j];
#pragma unroll
    for (int i = 0; i < 64; ++i) acc += t[g][i] * root[i * 64 + j];
    hn[node * 64 + j] = fmaxf(acc, 0.f);
}

// ---------------- output head ------------------------------------------------
__global__ void k_out(const float* __restrict__ h, const float* __restrict__ oW,
                      const float* __restrict__ ob, float* __restrict__ out) {
    int wg = (blockIdx.x * 256 + threadIdx.x) >> 6;
    int lane = threadIdx.x & 63;
    if (wg >= N_NODES) return;
    float p = h[wg * 64 + lane] * oW[lane];
#pragma unroll
    for (int s = 32; s > 0; s >>= 1) p += __shfl_xor(p, s);
    if (lane == 0) out[wg] = p + ob[0];
}

__global__ void k_sentinel(float* out) { out[0] = 1e30f; }

extern "C" void kernel_launch(void* const* d_in, const int* in_sizes, int n_in,
                              void* d_out, int out_size, void* d_ws, size_t ws_size,
                              hipStream_t stream) {
    const float* x          = (const float*)d_in[0];
    const float* edge_attr  = (const float*)d_in[1];
    const float* conditions = (const float*)d_in[2];
    const float* scale      = (const float*)d_in[3];
    const int*   edge_index = (const int*)d_in[4];
    const int*   batch      = (const int*)d_in[5];
    const float* nW1 = (const float*)d_in[6];  const float* nb1 = (const float*)d_in[7];
    const float* nW2 = (const float*)d_in[8];  const float* nb2 = (const float*)d_in[9];
    const float* cW1 = (const float*)d_in[10]; const float* cb1 = (const float*)d_in[11];
    const float* cW2 = (const float*)d_in[12]; const float* cb2 = (const float*)d_in[13];
    const float* kW1 = (const float*)d_in[14]; const float* kb1 = (const float*)d_in[15];
    const float* kW2 = (const float*)d_in[16]; const float* kb2 = (const float*)d_in[17];
    const float* kW3 = (const float*)d_in[18]; const float* kb3 = (const float*)d_in[19];
    const float* root = (const float*)d_in[20]; const float* conv_bias = (const float*)d_in[21];
    const float* oW  = (const float*)d_in[22]; const float* ob  = (const float*)d_in[23];
    float* out = (float*)d_out;

    char* ws = (char*)d_ws;
    size_t off = 0;
    auto alloc = [&](size_t bytes) -> char* {
        char* p = ws + off;
        off += (bytes + 255) & ~(size_t)255;
        return p;
    };
    float* h_a  = (float*)alloc((size_t)N_NODES * 64 * 4);
    float* h_b  = (float*)alloc((size_t)N_NODES * 64 * 4);
    float* agg  = (float*)alloc((size_t)N_NODES * 64 * 4);
    float* u    = (float*)alloc(256 * 4);
    float* deg  = (float*)alloc((size_t)N_NODES * 4);
    f16*   k2   = (f16*)alloc((size_t)EPAD * 256 * 2);
    f16*   kW3P = (f16*)alloc((size_t)4096 * 256 * 2);
    float* kb3P = (float*)alloc(4096 * 4);
    // total ~43 MB

    if (off > ws_size) {  // workspace too small: distinct sentinel
        k_sentinel<<<1, 1, 0, stream>>>(out);
        return;
    }

    hipMemsetAsync(deg, 0, (size_t)N_NODES * 4, stream);
    k_node_enc<<<2500, 256, 0, stream>>>(x, nW1, nb1, nW2, nb2, h_a);
    k_cond_enc<<<1, 256, 0, stream>>>(conditions, scale, cW1, cb1, cW2, cb2, u, out + N_NODES);
    k_deg<<<(N_EDGES + 255) / 256, 256, 0, stream>>>(edge_index + N_EDGES, deg);
    k_deg_inv<<<(N_NODES + 255) / 256, 256, 0, stream>>>(deg);
    k_permute<<<64, 256, 0, stream>>>(kW3, kb3, kW3P, kb3P);
    k_edge12<<<EPAD / 16, 256, 0, stream>>>(edge_attr, edge_index, batch, u, kW1, kb1, kW2, kb2, k2);

    float* hc = h_a; float* hn = h_b;
    for (int l = 0; l < 3; ++l) {
        hipMemsetAsync(agg, 0, (size_t)N_NODES * 64 * 4, stream);
        k_fused<<<dim3(EPAD / 128, CSPLIT), 256, 0, stream>>>(k2, kW3P, kb3P, hc, edge_index, deg, agg);
        k_update<<<2500, 256, 0, stream>>>(agg, hc, root, conv_bias, hn);
        float* tmp = hc; hc = hn; hn = tmp;
    }
    k_out<<<2500, 256, 0, stream>>>(hc, oW, ob, out);
}

// Round 7
// 951.739 us; speedup vs baseline: 1.6373x; 1.6373x over previous
//
#include <hip/hip_runtime.h>
#include <hip/hip_fp16.h>

#define N_NODES 10000
#define N_EDGES 60000
#define EPAD    60032   // multiple of 128
#define CSPLIT  2
#define CT_PER  32      // 64 / CSPLIT

typedef _Float16 f16;
typedef f16 f16x8 __attribute__((ext_vector_type(8)));
typedef float f32x4 __attribute__((ext_vector_type(4)));

__device__ __forceinline__ void gload16(const void* g, void* l) {
    __builtin_amdgcn_global_load_lds((const __attribute__((address_space(1))) unsigned int*)g,
                                     (__attribute__((address_space(3))) unsigned int*)l, 16, 0, 0);
}

// combine a,b over xor-mask m: lanes with (lane&m)==0 end with a-pair-sum, else b-pair-sum
__device__ __forceinline__ float foldp(float a, float b, int m, int lane) {
    float x = (lane & m) ? b : a;
    float y = (lane & m) ? a : b;
    return x + __shfl_xor(y, m);
}

// ---------------- node encoder: h = relu(x@nW1+nb1)@nW2+nb2 ----------------
__global__ void k_node_enc(const float* __restrict__ x, const float* __restrict__ W1,
                           const float* __restrict__ b1, const float* __restrict__ W2,
                           const float* __restrict__ b2, float* __restrict__ h) {
    __shared__ float t[4][64];
    int g = threadIdx.x >> 6, j = threadIdx.x & 63;
    int node = blockIdx.x * 4 + g;
    float acc = b1[j];
#pragma unroll
    for (int i = 0; i < 6; ++i) acc += x[node * 6 + i] * W1[i * 64 + j];
    t[g][j] = fmaxf(acc, 0.f);
    __syncthreads();
    float acc2 = b2[j];
#pragma unroll
    for (int i = 0; i < 64; ++i) acc2 += t[g][i] * W2[i * 64 + j];
    h[node * 64 + j] = acc2;
}

// ---------------- condition encoder -----------------------------------------
__global__ void k_cond_enc(const float* __restrict__ cond, const float* __restrict__ scl,
                           const float* __restrict__ W1, const float* __restrict__ b1,
                           const float* __restrict__ W2, const float* __restrict__ b2,
                           float* __restrict__ u, float* __restrict__ out_u) {
    __shared__ float t[4][64];
    __shared__ float cat[4][14];
    int g = threadIdx.x >> 6, j = threadIdx.x & 63;
    if (threadIdx.x < 56) {
        int b = threadIdx.x / 14, i = threadIdx.x % 14;
        cat[b][i] = (i < 10) ? cond[b * 10 + i] : scl[b * 4 + (i - 10)];
    }
    __syncthreads();
    float acc = b1[j];
#pragma unroll
    for (int i = 0; i < 14; ++i) acc += cat[g][i] * W1[i * 64 + j];
    t[g][j] = fmaxf(acc, 0.f);
    __syncthreads();
    float acc2 = b2[j];
#pragma unroll
    for (int i = 0; i < 64; ++i) acc2 += t[g][i] * W2[i * 64 + j];
    u[g * 64 + j] = acc2;
    out_u[g * 64 + j] = acc2;
}

// ---------------- degree -----------------------------------------------------
__global__ void k_deg(const int* __restrict__ dst, float* __restrict__ deg) {
    int e = blockIdx.x * 256 + threadIdx.x;
    if (e < N_EDGES) atomicAdd(&deg[dst[e]], 1.0f);
}
__global__ void k_deg_inv(float* __restrict__ deg) {
    int n = blockIdx.x * 256 + threadIdx.x;
    if (n < N_NODES) deg[n] = 1.0f / fmaxf(deg[n], 1.0f);
}

// ------- permute kW3 into FRAGMENT-ORDERED K-HALF tiles + kb3P ---------------
// halves offset = ct*16384 + kh*8192 + ((nf*4+ks4)*64 + kg*16 + rl)*8
// element j there = kW3[k][i*64+ct] with i=nf*16+rl, k=(kh*4+ks4)*32+kg*8+j
__global__ void k_permute(const float* __restrict__ kW3, const float* __restrict__ kb3,
                          f16* __restrict__ kW3P, float* __restrict__ kb3P) {
    __shared__ float T[256][65];
    int i = blockIdx.x;                 // 0..63 (inner input index)
    int o = threadIdx.x & 63, kq = threadIdx.x >> 6;
    for (int kk = 0; kk < 64; ++kk) {
        int k = kk * 4 + kq;
        T[k][o] = kW3[(size_t)k * 4096 + i * 64 + o];
    }
    if (threadIdx.x < 64) kb3P[threadIdx.x * 64 + i] = kb3[i * 64 + threadIdx.x];
    __syncthreads();
    int ow = threadIdx.x >> 2, kc = (threadIdx.x & 3) * 64;
    int nf = i >> 4, rl = i & 15;
    for (int c = 0; c < 8; ++c) {
        int k0 = kc + c * 8;
        int ks = k0 >> 5, kh = ks >> 2, ks4 = ks & 3, kg = (k0 >> 3) & 3;
        size_t off = (size_t)ow * 16384 + kh * 8192 + ((nf * 4 + ks4) * 64 + kg * 16 + rl) * 8;
        f16x8 v;
#pragma unroll
        for (int jj = 0; jj < 8; ++jj) v[jj] = (f16)T[k0 + jj][ow];
        *(f16x8*)(kW3P + off) = v;
    }
}

// ---------------- fused edge MLP (k1 in LDS, k2 fp16 out) --------------------
__global__ __launch_bounds__(256) void k_edge12(const float* __restrict__ ea, const int* __restrict__ ei,
                                                const int* __restrict__ batch, const float* __restrict__ u,
                                                const float* __restrict__ W1, const float* __restrict__ b1,
                                                const float* __restrict__ W2, const float* __restrict__ b2,
                                                f16* __restrict__ k2) {
    __shared__ float u_s[256];
    __shared__ float ea_s[16][6];
    __shared__ int b_s[16];
    __shared__ float k1_s[16][128];
    int tid = threadIdx.x;
    int e0 = blockIdx.x * 16;
    u_s[tid] = u[tid];
    if (tid < 96) {
        int e = tid / 6, i = tid % 6;
        int eg = e0 + e;
        ea_s[e][i] = (eg < N_EDGES) ? ea[(size_t)eg * 6 + i] : 0.f;
    }
    if (tid < 16) {
        int eg = e0 + tid;
        b_s[tid] = (eg < N_EDGES) ? batch[ei[eg]] : 0;
    }
    __syncthreads();
    int j = tid & 127;
#pragma unroll 1
    for (int p = 0; p < 8; ++p) {
        int e = p * 2 + (tid >> 7);
        float acc = b1[j];
#pragma unroll
        for (int i = 0; i < 6; ++i) acc += ea_s[e][i] * W1[i * 128 + j];
        const float* ur = u_s + b_s[e] * 64;
#pragma unroll
        for (int i = 0; i < 64; ++i) acc += ur[i] * W1[(6 + i) * 128 + j];
        k1_s[e][j] = fmaxf(acc, 0.f);
    }
    __syncthreads();
    float acc2[16];
#pragma unroll
    for (int e = 0; e < 16; ++e) acc2[e] = b2[tid];
    for (int i = 0; i < 128; ++i) {
        float w = W2[(size_t)i * 256 + tid];
#pragma unroll
        for (int e = 0; e < 16; ++e) acc2[e] += k1_s[e][i] * w;
    }
#pragma unroll
    for (int e = 0; e < 16; ++e) {
        int eg = e0 + e;
        k2[(size_t)eg * 256 + tid] = (f16)((eg < N_EDGES) ? fmaxf(acc2[e], 0.f) : 0.f);
    }
}

// ---- fused GEMM + message dot + scatter-mean --------------------------------
// block = 128 edges x CT_PER col-tiles; A + h*dinv in regs; B double-buffered
// per K-HALF (16 KB) via global_load_lds; 1 barrier/half; bias from global;
// fold-reduce epilogue; 8-ct (32B-sector) deferred atomic flush.
// NOTE: no min-waves launch bound — a VGPR cap below ~124 forces the A/h
// register working set into scratch (round 6: 1.1 GB traffic, 2x slower).
__global__ __launch_bounds__(256) void k_fused(const f16* __restrict__ A, const f16* __restrict__ Bf,
                                               const float* __restrict__ kb3P, const float* __restrict__ h,
                                               const int* __restrict__ ei, const float* __restrict__ dinv,
                                               float* __restrict__ agg) {
    __shared__ __align__(16) f16 lB[2][8192];    // 2 x 16 KB
    __shared__ int src_s[128];
    __shared__ int dst_s[128];
    __shared__ float dinv_s[128];
    int tid = threadIdx.x, wave = tid >> 6, lane = tid & 63;
    int m0 = blockIdx.x * 128;
    int ct0 = blockIdx.y * CT_PER;
    if (tid < 128) {
        int eg = m0 + tid; int s = 0, d = 0; float dv = 0.f;
        if (eg < N_EDGES) { s = ei[eg]; d = ei[N_EDGES + eg]; dv = dinv[d]; }
        src_s[tid] = s; dst_s[tid] = d; dinv_s[tid] = dv;
    }
    // stage segment 0 (= ct0, k-half 0)
    {
        const f16* bp = Bf + (size_t)(ct0 * 2) * 8192;
#pragma unroll
        for (int q = 0; q < 4; ++q)
            gload16(bp + (q * 256 + tid) * 8, &lB[0][(q * 256 + wave * 64) * 8]);
    }
    __syncthreads();   // seg0 drained + src_s visible
    // A fragments: rows wave*32 + mf*16 + (lane&15), k-chunk (lane>>4)*8 + ks*32
    f16x8 a[2][8];
#pragma unroll
    for (int mf = 0; mf < 2; ++mf) {
        const f16* ap = A + (size_t)(m0 + wave * 32 + mf * 16 + (lane & 15)) * 256 + (lane >> 4) * 8;
#pragma unroll
        for (int ks = 0; ks < 8; ++ks) a[mf][ks] = *(const f16x8*)(ap + ks * 32);
    }
    // h rows (pre-scaled by dinv) in regs
    float hsr[2][4][4];
#pragma unroll
    for (int mf = 0; mf < 2; ++mf)
#pragma unroll
        for (int jj = 0; jj < 4; ++jj) {
            int el = wave * 32 + mf * 16 + (lane >> 4) * 4 + jj;
            const float* hp = h + (size_t)src_s[el] * 64 + (lane & 15);
            float dv = dinv_s[el];
#pragma unroll
            for (int nf = 0; nf < 4; ++nf) hsr[mf][jj][nf] = hp[nf * 16] * dv;
        }
    const float* bias_p = kb3P + ct0 * 64 + (lane & 15);
    int cur = 0;
#pragma unroll 1
    for (int cto = 0; cto < CT_PER; cto += 8) {
        float w8[8];
#pragma unroll
        for (int q8 = 0; q8 < 8; ++q8) {
            int ctl = cto + q8;
            // acc init = permuted bias (column-constant across rows)
            f32x4 acc[2][4];
#pragma unroll
            for (int nf = 0; nf < 4; ++nf) {
                float bv = bias_p[ctl * 64 + nf * 16];
                acc[0][nf] = {bv, bv, bv, bv};
                acc[1][nf] = {bv, bv, bv, bv};
            }
#pragma unroll
            for (int kh = 0; kh < 2; ++kh) {
                int seg = ctl * 2 + kh;
                if (seg + 1 < CT_PER * 2) {   // prefetch next k-half into alt buffer
                    const f16* bp = Bf + (size_t)(ct0 * 2 + seg + 1) * 8192;
#pragma unroll
                    for (int q = 0; q < 4; ++q)
                        gload16(bp + (q * 256 + tid) * 8, &lB[cur ^ 1][(q * 256 + wave * 64) * 8]);
                }
                const f16* lb = lB[cur];
#pragma unroll
                for (int ks4 = 0; ks4 < 4; ++ks4) {
                    f16x8 bf[4];
#pragma unroll
                    for (int nf = 0; nf < 4; ++nf)
                        bf[nf] = *(const f16x8*)(lb + (nf * 4 + ks4) * 512 + lane * 8);
#pragma unroll
                    for (int mf = 0; mf < 2; ++mf)
#pragma unroll
                        for (int nf = 0; nf < 4; ++nf)
                            acc[mf][nf] = __builtin_amdgcn_mfma_f32_16x16x32_f16(a[mf][kh * 4 + ks4], bf[nf], acc[mf][nf], 0, 0, 0);
                }
                cur ^= 1;
                __syncthreads();   // drains next-half loads; WAR on read buffer
            }
            // per-lane partials then fold-reduce (8 shfl total)
            float v[8];
#pragma unroll
            for (int mf = 0; mf < 2; ++mf)
#pragma unroll
                for (int jj = 0; jj < 4; ++jj)
                    v[mf * 4 + jj] = acc[mf][0][jj] * hsr[mf][jj][0] + acc[mf][1][jj] * hsr[mf][jj][1]
                                   + acc[mf][2][jj] * hsr[mf][jj][2] + acc[mf][3][jj] * hsr[mf][jj][3];
            float t0 = foldp(v[0], v[1], 1, lane);
            float t1 = foldp(v[2], v[3], 1, lane);
            float t2 = foldp(v[4], v[5], 1, lane);
            float t3 = foldp(v[6], v[7], 1, lane);
            float u0 = foldp(t0, t1, 2, lane);
            float u1 = foldp(t2, t3, 2, lane);
            float s0 = foldp(u0, u1, 4, lane);
            s0 += __shfl_xor(s0, 8);
            w8[q8] = s0;
        }
        // flush 8 cts = one 32B sector per edge (pad edges: dinv=0 -> adds 0.0)
        if (!(lane & 8)) {
            int mf = (lane >> 2) & 1, jj = lane & 3;
            int el = wave * 32 + mf * 16 + (lane >> 4) * 4 + jj;
            float* ap2 = agg + (size_t)dst_s[el] * 64 + ct0 + cto;
#pragma unroll
            for (int q8 = 0; q8 < 8; ++q8) atomicAdd(ap2 + q8, w8[q8]);
        }
    }
}

// ---------------- node update: h' = relu(agg + h@root + bias) ----------------
__global__ void k_update(const float* __restrict__ agg, const float* __restrict__ h,
                         const float* __restrict__ root, const float* __restrict__ bias,
                         float* __restrict__ hn) {
    __shared__ float t[4][64];
    int g = threadIdx.x >> 6, j = threadIdx.x & 63;
    int node = blockIdx.x * 4 + g;
    t[g][j] = h[node * 64 + j];
    __syncthreads();
    float acc = agg[node * 64 + j] + bias[j];
#pragma unroll
    for (int i = 0; i < 64; ++i) acc += t[g][i] * root[i * 64 + j];
    hn[node * 64 + j] = fmaxf(acc, 0.f);
}

// ---------------- output head ------------------------------------------------
__global__ void k_out(const float* __restrict__ h, const float* __restrict__ oW,
                      const float* __restrict__ ob, float* __restrict__ out) {
    int wg = (blockIdx.x * 256 + threadIdx.x) >> 6;
    int lane = threadIdx.x & 63;
    if (wg >= N_NODES) return;
    float p = h[wg * 64 + lane] * oW[lane];
#pragma unroll
    for (int s = 32; s > 0; s >>= 1) p += __shfl_xor(p, s);
    if (lane == 0) out[wg] = p + ob[0];
}

__global__ void k_sentinel(float* out) { out[0] = 1e30f; }

extern "C" void kernel_launch(void* const* d_in, const int* in_sizes, int n_in,
                              void* d_out, int out_size, void* d_ws, size_t ws_size,
                              hipStream_t stream) {
    const float* x          = (const float*)d_in[0];
    const float* edge_attr  = (const float*)d_in[1];
    const float* conditions = (const float*)d_in[2];
    const float* scale      = (const float*)d_in[3];
    const int*   edge_index = (const int*)d_in[4];
    const int*   batch      = (const int*)d_in[5];
    const float* nW1 = (const float*)d_in[6];  const float* nb1 = (const float*)d_in[7];
    const float* nW2 = (const float*)d_in[8];  const float* nb2 = (const float*)d_in[9];
    const float* cW1 = (const float*)d_in[10]; const float* cb1 = (const float*)d_in[11];
    const float* cW2 = (const float*)d_in[12]; const float* cb2 = (const float*)d_in[13];
    const float* kW1 = (const float*)d_in[14]; const float* kb1 = (const float*)d_in[15];
    const float* kW2 = (const float*)d_in[16]; const float* kb2 = (const float*)d_in[17];
    const float* kW3 = (const float*)d_in[18]; const float* kb3 = (const float*)d_in[19];
    const float* root = (const float*)d_in[20]; const float* conv_bias = (const float*)d_in[21];
    const float* oW  = (const float*)d_in[22]; const float* ob  = (const float*)d_in[23];
    float* out = (float*)d_out;

    char* ws = (char*)d_ws;
    size_t off = 0;
    auto alloc = [&](size_t bytes) -> char* {
        char* p = ws + off;
        off += (bytes + 255) & ~(size_t)255;
        return p;
    };
    float* h_a  = (float*)alloc((size_t)N_NODES * 64 * 4);
    float* h_b  = (float*)alloc((size_t)N_NODES * 64 * 4);
    float* agg  = (float*)alloc((size_t)N_NODES * 64 * 4);
    float* u    = (float*)alloc(256 * 4);
    float* deg  = (float*)alloc((size_t)N_NODES * 4);
    f16*   k2   = (f16*)alloc((size_t)EPAD * 256 * 2);
    f16*   kW3P = (f16*)alloc((size_t)4096 * 256 * 2);
    float* kb3P = (float*)alloc(4096 * 4);
    // total ~43 MB

    if (off > ws_size) {  // workspace too small: distinct sentinel
        k_sentinel<<<1, 1, 0, stream>>>(out);
        return;
    }

    hipMemsetAsync(deg, 0, (size_t)N_NODES * 4, stream);
    k_node_enc<<<2500, 256, 0, stream>>>(x, nW1, nb1, nW2, nb2, h_a);
    k_cond_enc<<<1, 256, 0, stream>>>(conditions, scale, cW1, cb1, cW2, cb2, u, out + N_NODES);
    k_deg<<<(N_EDGES + 255) / 256, 256, 0, stream>>>(edge_index + N_EDGES, deg);
    k_deg_inv<<<(N_NODES + 255) / 256, 256, 0, stream>>>(deg);
    k_permute<<<64, 256, 0, stream>>>(kW3, kb3, kW3P, kb3P);
    k_edge12<<<EPAD / 16, 256, 0, stream>>>(edge_attr, edge_index, batch, u, kW1, kb1, kW2, kb2, k2);

    float* hc = h_a; float* hn = h_b;
    for (int l = 0; l < 3; ++l) {
        hipMemsetAsync(agg, 0, (size_t)N_NODES * 64 * 4, stream);
        k_fused<<<dim3(EPAD / 128, CSPLIT), 256, 0, stream>>>(k2, kW3P, kb3P, hc, edge_index, deg, agg);
        k_update<<<2500, 256, 0, stream>>>(agg, hc, root, conv_bias, hn);
        float* tmp = hc; hc = hn; hn = tmp;
    }
    k_out<<<2500, 256, 0, stream>>>(hc, oW, ob, out);
}